// Round 4
// baseline (262.697 us; speedup 1.0000x reference)
//
#include <hip/hip_runtime.h>
#include <stdint.h>

typedef unsigned short u16;
typedef __bf16 bf16x8 __attribute__((ext_vector_type(8)));
typedef unsigned short u16x8 __attribute__((ext_vector_type(8)));
typedef unsigned short u16x4 __attribute__((ext_vector_type(4)));
typedef float f32x4 __attribute__((ext_vector_type(4)));
typedef uint32_t u32v4 __attribute__((ext_vector_type(4)));

#define LOG2E 1.4426950408889634f

typedef const __attribute__((address_space(1))) uint32_t as1_u32;
typedef __attribute__((address_space(3))) uint32_t as3_u32;

// float -> bf16 round-to-nearest-even
__device__ __forceinline__ u16 f2bf(float f) {
  union { float f; uint32_t i; } v; v.f = f;
  uint32_t r = (v.i + 0x7fffu + ((v.i >> 16) & 1u)) >> 16;
  return (u16)r;
}
__device__ __forceinline__ float bf2f(u16 u) {
  union { uint32_t i; float f; } v; v.i = ((uint32_t)u) << 16; return v.f;
}

// async global->LDS, 16B/lane. LDS dest = wave-uniform base; HW scatters
// lane i to base + i*16B (matches As/Bs row layout: row stride 64B).
__device__ __forceinline__ void gld_lds16(const void* g, void* l) {
  as1_u32* gp = (as1_u32*)((uintptr_t)g);
  as3_u32* lp = (as3_u32*)(uint32_t)(uintptr_t)(l);
  __builtin_amdgcn_global_load_lds(gp, lp, 16, 0, 0);
}

// ---------------------------------------------------------------------------
// Kernel 0: f32 -> bf16 convert.
// ---------------------------------------------------------------------------
__global__ __launch_bounds__(256) void f32_to_bf16(
    const float* __restrict__ x, const float* __restrict__ wq,
    const float* __restrict__ wk, const float* __restrict__ wv,
    u16* __restrict__ xc, u16* __restrict__ wqc,
    u16* __restrict__ wkc, u16* __restrict__ wvc) {
  const int z = blockIdx.y;
  const float* src = z == 0 ? x : (z == 1 ? wq : (z == 2 ? wk : wv));
  u16* dst = z == 0 ? xc : (z == 1 ? wqc : (z == 2 ? wkc : wvc));
  const int n = z == 0 ? (1 << 22) : (1 << 20);

  const int idx = (blockIdx.x * 256 + (int)threadIdx.x) * 8;
  if (idx >= n) return;
  const f32x4 a = *(const f32x4*)&src[idx];
  const f32x4 b = *(const f32x4*)&src[idx + 4];
  u16x8 o;
#pragma unroll
  for (int j = 0; j < 4; j++) { o[j] = f2bf(a[j]); o[j + 4] = f2bf(b[j]); }
  *(u16x8*)&dst[idx] = o;
}

// ---------------------------------------------------------------------------
// Kernel 1: QKV GEMM, 128x128 tile, BK=32, m97-style global_load_lds staging.
//  z=0/1: q/k = x @ W^T -> [4096][1024]
//  z=2  : vt = Wv @ x^T -> [1024][4096] (coalesced store), with the key
//         bit2<->bit3 swap folded into the store column (within each
//         16-token block) so flash's PV B-frags read vt linearly.
// ---------------------------------------------------------------------------
__global__ __launch_bounds__(256) void qkv_gemm(
    const u16* __restrict__ xc, const u16* __restrict__ wqc,
    const u16* __restrict__ wkc, const u16* __restrict__ wvc,
    u16* __restrict__ qo, u16* __restrict__ ko, u16* __restrict__ vt) {
  __shared__ __align__(16) u16 As[128 * 32];
  __shared__ __align__(16) u16 Bs[128 * 32];

  const int tid = threadIdx.x;
  const int lane = tid & 63;
  const int w = tid >> 6;
  const int wm = w >> 1, wn = w & 1;
  const int quad = lane >> 4, m16 = lane & 15;
  const int which = blockIdx.z;

  const u16* __restrict__ Ap;
  const u16* __restrict__ Bp;
  int m0, n0;
  if (which == 2) {
    Ap = wvc; Bp = xc;
    m0 = blockIdx.x * 128;   // Wv rows (1024)
    n0 = blockIdx.y * 128;   // x rows (4096)
  } else {
    Ap = xc; Bp = which == 0 ? wqc : wkc;
    m0 = blockIdx.y * 128;   // x rows
    n0 = blockIdx.x * 128;   // W rows
  }

  const f32x4 z4 = {0.f, 0.f, 0.f, 0.f};
  f32x4 acc[4][4];
#pragma unroll
  for (int i = 0; i < 4; i++)
#pragma unroll
    for (int j = 0; j < 4; j++) acc[i][j] = z4;

  const int rowA = m0 + w * 32 + (lane >> 2);
  const int rowB = n0 + w * 32 + (lane >> 2);
  const int cch = (lane & 3) * 8;

  for (int k0 = 0; k0 < 1024; k0 += 32) {
    __syncthreads();  // prior MFMA reads of As/Bs complete
#pragma unroll
    for (int i = 0; i < 2; i++) {
      gld_lds16(&Ap[(size_t)(rowA + i * 16) * 1024 + k0 + cch],
                &As[(w * 32 + i * 16) * 32]);
      gld_lds16(&Bp[(size_t)(rowB + i * 16) * 1024 + k0 + cch],
                &Bs[(w * 32 + i * 16) * 32]);
    }
    __syncthreads();  // drains vmcnt (compiler-inserted) -> tiles ready

    bf16x8 af[4], bfr[4];
#pragma unroll
    for (int t = 0; t < 4; t++) {
      af[t]  = *(const bf16x8*)&As[(wm * 64 + t * 16 + m16) * 32 + quad * 8];
      bfr[t] = *(const bf16x8*)&Bs[(wn * 64 + t * 16 + m16) * 32 + quad * 8];
    }
#pragma unroll
    for (int mt = 0; mt < 4; mt++)
#pragma unroll
      for (int nt = 0; nt < 4; nt++)
        acc[mt][nt] = __builtin_amdgcn_mfma_f32_16x16x32_bf16(
            af[mt], bfr[nt], acc[mt][nt], 0, 0, 0);
  }

  // Epilogue. C/D layout: col(n)=lane&15, row(m)=quad*4+reg.
  if (which < 2) {
    u16* __restrict__ out = which == 0 ? qo : ko;
#pragma unroll
    for (int mt = 0; mt < 4; mt++) {
      const int row = m0 + wm * 64 + mt * 16 + quad * 4;
#pragma unroll
      for (int nt = 0; nt < 4; nt++) {
        const int n = n0 + wn * 64 + nt * 16 + m16;
        f32x4 a = acc[mt][nt];
#pragma unroll
        for (int r = 0; r < 4; r++)
          out[(size_t)(row + r) * 1024 + n] = f2bf(a[r]);
      }
    }
  } else {
    // vt store with swap23 on the within-16 token index (involution):
    // column (...|m16p) holds V[token ...|m16] so flash reads vt linearly
    // and gets the key order its P-fragments produce.
    const int m16p = (m16 & 3) | ((m16 & 4) << 1) | ((m16 & 8) >> 1);
#pragma unroll
    for (int mt = 0; mt < 4; mt++) {
      const int row = m0 + wm * 64 + mt * 16 + quad * 4;  // d index
#pragma unroll
      for (int nt = 0; nt < 4; nt++) {
        const int n = n0 + wn * 64 + nt * 16 + m16p;      // x row (permuted)
        f32x4 a = acc[mt][nt];
#pragma unroll
        for (int r = 0; r < 4; r++)
          vt[(size_t)(row + r) * 4096 + n] = f2bf(a[r]);
      }
    }
  }
}

// ---------------------------------------------------------------------------
// Kernel 2: standalone RoPE, in-place on q/k.
// ---------------------------------------------------------------------------
__global__ __launch_bounds__(256) void rope_inplace(u16* __restrict__ qb,
                                                    u16* __restrict__ kb) {
  u16* buf = blockIdx.y == 0 ? qb : kb;
  const int p = blockIdx.x * 256 + (int)threadIdx.x;
  const int nidx = p * 2;
  const int row = nidx >> 10;
  const int col = nidx & 1023;
  const int i = (col & 63) >> 1;
  const int t = row & 2047;
  const float theta = exp2f(-(float)i * 0.02595256324130752f);
  const float ang = (float)t * theta;
  float s, c;
  sincosf(ang, &s, &c);
  const float a0 = bf2f(buf[(size_t)row * 1024 + col]);
  const float a1 = bf2f(buf[(size_t)row * 1024 + col + 1]);
  buf[(size_t)row * 1024 + col]     = f2bf(a0 * c - a1 * s);
  buf[(size_t)row * 1024 + col + 1] = f2bf(a1 * c + a0 * s);
}

// ---------------------------------------------------------------------------
// Kernel 3: causal flash attention — LDS-FREE, BARRIER-FREE, 1 wave/block.
// R1-R3 lesson: cost was a constant ~1.6us per 64-key tile, set by the
// per-CU LDS pipe (staging writes + 4x-redundant fragment reads + 4.45M
// conflict cycles) and barrier lock-step; occupancy/HBM changes were flat.
// K/V are L2-resident (FETCH=12MB), so fragments are read DIRECTLY from
// global/L2: K A-frags are contiguous 16B/lane from kg rows; V B-frags are
// contiguous 16B/lane from vt rows (key swap23 pre-applied by qkv_gemm).
// Each wave (64 threads) owns 16 q-rows, runs independently: grid 4096.
// id map: XCD = id&7 sees 4 heads (2MB K+V < 4MB L2); per CU the wave set
// mixes qt=c and 31-c so total trip counts balance; nr trimmed per-wave.
// In-register P (T12), l via ones-MFMA, NO-RESCALE softmax as before.
// ---------------------------------------------------------------------------
__global__ __launch_bounds__(64, 4) void flash_attn(
    const u16* __restrict__ qg, const u16* __restrict__ kg,
    const u16* __restrict__ vt, float* __restrict__ out) {
  const int lane = threadIdx.x;
  const int quad = lane >> 4, m16 = lane & 15;

  // id -> (XCD, cu-slot c, j); j -> (v_loc, ws); qt pairs c with 31-c.
  const int id   = (int)blockIdx.x;
  const int X    = id & 7;
  const int rem  = id >> 3;          // 0..511 within XCD
  const int c    = rem & 31;
  const int j    = rem >> 5;         // 0..15
  const int vloc = j & 3;
  const int ws   = j >> 2;           // q-row slice within the 64-row tile
  const int qt   = (vloc & 1) ? (31 - c) : c;
  const int v    = X * 4 + vloc;     // (b,h) combo
  const int h    = v & 15;
  const int b    = v >> 4;

  const size_t base  = (size_t)b * 2048 * 1024 + (size_t)h * 64;
  const size_t vbase = (size_t)(h * 64) * 4096 + (size_t)b * 2048;
  const float SC = 0.03125f * LOG2E;
  const f32x4 z4 = {0.f, 0.f, 0.f, 0.f};

  union { u16x8 u; bf16x8 f; } ones;
#pragma unroll
  for (int k = 0; k < 8; k++) ones.u[k] = 0x3F80;  // bf16 1.0

  const int q0    = qt * 64;
  const int qrow0 = q0 + ws * 16 + quad * 4;  // O store rows
  const int qcol  = q0 + ws * 16 + m16;       // this lane's softmax q
  // rounds of 128 keys, trimmed to this wave's own 16 rows
  const int nr    = ((q0 + ws * 16 + 15) >> 7) + 1;

  // Q fragments straight from global (L2-hit; once per wave).
  const u16* qsrc = &qg[base + (size_t)(q0 + ws * 16 + m16) * 1024 + quad * 8];
  const bf16x8 qf0 = *(const bf16x8*)qsrc;
  const bf16x8 qf1 = *(const bf16x8*)(qsrc + 32);

  f32x4 l4 = z4;  // l[r] = denom for q row qrow0+r (via ones-MFMA)
  f32x4 O[4];
#pragma unroll
  for (int d = 0; d < 4; d++) O[d] = z4;

  for (int rr = 0; rr < nr; ++rr) {
    const int k0 = rr * 128;

    // S^T = K Q^T over 128 keys; K A-frags direct from L2.
    f32x4 S[8];
#pragma unroll
    for (int nt = 0; nt < 8; nt++) {
      const u16* kp = &kg[base + (size_t)(k0 + nt * 16 + m16) * 1024 + quad * 8];
      const bf16x8 kf0 = *(const bf16x8*)kp;
      const bf16x8 kf1 = *(const bf16x8*)(kp + 32);
      S[nt] = __builtin_amdgcn_mfma_f32_16x16x32_bf16(kf0, qf0, z4, 0, 0, 0);
      S[nt] = __builtin_amdgcn_mfma_f32_16x16x32_bf16(kf1, qf1, S[nt], 0, 0, 0);
    }

    // p = exp2(s*SC); mask only on the last round (covers diag + dead keys;
    // 16-row groups never straddle a 128 boundary, so earlier rounds are
    // always fully below the diagonal).
    const bool lastr = (rr == nr - 1);
    uint32_t W[16];
#pragma unroll
    for (int nt = 0; nt < 8; nt++) {
      float p[4];
#pragma unroll
      for (int r = 0; r < 4; r++) {
        float e = exp2f(S[nt][r] * SC);
        const int key = k0 + nt * 16 + quad * 4 + r;
        if (lastr && key > qcol) e = 0.f;
        p[r] = e;
      }
      uint32_t w0, w1;
      asm("v_cvt_pk_bf16_f32 %0, %1, %2" : "=v"(w0) : "v"(p[0]), "v"(p[1]));
      asm("v_cvt_pk_bf16_f32 %0, %1, %2" : "=v"(w1) : "v"(p[2]), "v"(p[3]));
      W[2 * nt] = w0; W[2 * nt + 1] = w1;
    }

    // Assemble PV A-frags: one permlane32_swap pair per 32-key block.
    union { u32v4 u; bf16x8 f; } P[4];
#pragma unroll
    for (int ks = 0; ks < 4; ks++) {
      uint32_t a0 = W[4 * ks], b0 = W[4 * ks + 2];
      uint32_t a1 = W[4 * ks + 1], b1 = W[4 * ks + 3];
      asm("v_permlane32_swap_b32 %0, %1" : "+v"(a0), "+v"(b0));
      asm("v_permlane32_swap_b32 %0, %1" : "+v"(a1), "+v"(b1));
      P[ks].u = (u32v4){a0, a1, b0, b1};
    }

    // l += P * ones  (row sums of rounded P; same row indexing as O)
#pragma unroll
    for (int ks = 0; ks < 4; ks++)
      l4 = __builtin_amdgcn_mfma_f32_16x16x32_bf16(P[ks].f, ones.f, l4,
                                                   0, 0, 0);

    // O += P V; V B-frags direct from L2 (vt rows, swap23 pre-applied).
#pragma unroll
    for (int dt = 0; dt < 4; dt++) {
#pragma unroll
      for (int ks = 0; ks < 4; ks++) {
        const bf16x8 vf = *(const bf16x8*)
            &vt[vbase + (size_t)(dt * 16 + m16) * 4096 + k0 + ks * 32 + quad * 8];
        O[dt] = __builtin_amdgcn_mfma_f32_16x16x32_bf16(P[ks].f, vf, O[dt],
                                                        0, 0, 0);
      }
    }
  }

  float inv[4];
#pragma unroll
  for (int r = 0; r < 4; r++) inv[r] = 1.0f / l4[r];

#pragma unroll
  for (int dt = 0; dt < 4; dt++)
#pragma unroll
    for (int r = 0; r < 4; r++)
      out[base + (size_t)(qrow0 + r) * 1024 + dt * 16 + m16] =
          O[dt][r] * inv[r];
}

extern "C" void kernel_launch(void* const* d_in, const int* in_sizes, int n_in,
                              void* d_out, int out_size, void* d_ws, size_t ws_size,
                              hipStream_t stream) {
  const float* x  = (const float*)d_in[0];
  const float* Wq = (const float*)d_in[1];
  const float* Wk = (const float*)d_in[2];
  const float* Wv = (const float*)d_in[3];
  u16* qb  = (u16*)d_ws;                    // [4096][1024] bf16
  u16* kb  = qb  + (size_t)4096 * 1024;     // [4096][1024] bf16
  u16* vtw = kb  + (size_t)4096 * 1024;     // [1024][4096] bf16 (V^T, swap23)
  u16* xc  = vtw + (size_t)4096 * 1024;     // bf16 inputs
  u16* wqc = xc  + (size_t)4096 * 1024;
  u16* wkc = wqc + (size_t)1024 * 1024;
  u16* wvc = wkc + (size_t)1024 * 1024;

  f32_to_bf16<<<dim3(2048, 4), 256, 0, stream>>>(x, Wq, Wk, Wv,
                                                 xc, wqc, wkc, wvc);
  qkv_gemm<<<dim3(8, 32, 3), 256, 0, stream>>>(xc, wqc, wkc, wvc,
                                               qb, kb, vtw);
  rope_inplace<<<dim3(8192, 2), 256, 0, stream>>>(qb, kb);
  flash_attn<<<dim3(4096, 1, 1), 64, 0, stream>>>(qb, kb, vtw, (float*)d_out);
}

// Round 5
// 153.487 us; speedup vs baseline: 1.7115x; 1.7115x over previous
//
#include <hip/hip_runtime.h>
#include <stdint.h>

typedef unsigned short u16;
typedef __bf16 bf16x8 __attribute__((ext_vector_type(8)));
typedef unsigned short u16x8 __attribute__((ext_vector_type(8)));
typedef unsigned short u16x4 __attribute__((ext_vector_type(4)));
typedef float f32x4 __attribute__((ext_vector_type(4)));
typedef uint32_t u32v4 __attribute__((ext_vector_type(4)));

#define LOG2E 1.4426950408889634f

typedef const __attribute__((address_space(1))) uint32_t as1_u32;
typedef __attribute__((address_space(3))) uint32_t as3_u32;

// float -> bf16 round-to-nearest-even
__device__ __forceinline__ u16 f2bf(float f) {
  union { float f; uint32_t i; } v; v.f = f;
  uint32_t r = (v.i + 0x7fffu + ((v.i >> 16) & 1u)) >> 16;
  return (u16)r;
}
__device__ __forceinline__ float bf2f(u16 u) {
  union { uint32_t i; float f; } v; v.i = ((uint32_t)u) << 16; return v.f;
}

// async global->LDS, 16B/lane. LDS dest = wave-uniform base; HW scatters
// lane i to base + i*16B.
__device__ __forceinline__ void gld_lds16(const void* g, void* l) {
  as1_u32* gp = (as1_u32*)((uintptr_t)g);
  as3_u32* lp = (as3_u32*)(uint32_t)(uintptr_t)(l);
  __builtin_amdgcn_global_load_lds(gp, lp, 16, 0, 0);
}

// raw v_exp_f32 (2^x), no libm clamp path — inputs bounded here
__device__ __forceinline__ float fast_exp2(float x) {
  float r;
  asm("v_exp_f32 %0, %1" : "=v"(r) : "v"(x));
  return r;
}

// ---------------------------------------------------------------------------
// Kernel 0: f32 -> bf16 convert.
// ---------------------------------------------------------------------------
__global__ __launch_bounds__(256) void f32_to_bf16(
    const float* __restrict__ x, const float* __restrict__ wq,
    const float* __restrict__ wk, const float* __restrict__ wv,
    u16* __restrict__ xc, u16* __restrict__ wqc,
    u16* __restrict__ wkc, u16* __restrict__ wvc) {
  const int z = blockIdx.y;
  const float* src = z == 0 ? x : (z == 1 ? wq : (z == 2 ? wk : wv));
  u16* dst = z == 0 ? xc : (z == 1 ? wqc : (z == 2 ? wkc : wvc));
  const int n = z == 0 ? (1 << 22) : (1 << 20);

  const int idx = (blockIdx.x * 256 + (int)threadIdx.x) * 8;
  if (idx >= n) return;
  const f32x4 a = *(const f32x4*)&src[idx];
  const f32x4 b = *(const f32x4*)&src[idx + 4];
  u16x8 o;
#pragma unroll
  for (int j = 0; j < 4; j++) { o[j] = f2bf(a[j]); o[j + 4] = f2bf(b[j]); }
  *(u16x8*)&dst[idx] = o;
}

// ---------------------------------------------------------------------------
// Kernel 1: QKV GEMM, 128x128 tile, BK=64 (halved barrier rounds vs BK=32),
// XOR-swizzled LDS: store chunk cc' = cc ^ (row&7) via pre-swizzled GLOBAL
// source address (global_load_lds writes linearly), read frags with the same
// XOR -> 2-way max bank aliasing (free) instead of the 8/16-way conflicts a
// linear 128B-row-stride layout has.
//  z=0/1: q/k = x @ W^T -> [4096][1024]
//  z=2  : vt = Wv @ x^T -> [1024][4096] (coalesced store), key bit2<->bit3
//         swap folded into the store column so flash reads vt linearly.
// ---------------------------------------------------------------------------
__global__ __launch_bounds__(256) void qkv_gemm(
    const u16* __restrict__ xc, const u16* __restrict__ wqc,
    const u16* __restrict__ wkc, const u16* __restrict__ wvc,
    u16* __restrict__ qo, u16* __restrict__ ko, u16* __restrict__ vt) {
  __shared__ __align__(16) u16 As[128 * 64];
  __shared__ __align__(16) u16 Bs[128 * 64];

  const int tid = threadIdx.x;
  const int lane = tid & 63;
  const int w = tid >> 6;
  const int wm = w >> 1, wn = w & 1;
  const int quad = lane >> 4, m16 = lane & 15;
  const int which = blockIdx.z;

  const u16* __restrict__ Ap;
  const u16* __restrict__ Bp;
  int m0, n0;
  if (which == 2) {
    Ap = wvc; Bp = xc;
    m0 = blockIdx.x * 128;   // Wv rows (1024)
    n0 = blockIdx.y * 128;   // x rows (4096)
  } else {
    Ap = xc; Bp = which == 0 ? wqc : wkc;
    m0 = blockIdx.y * 128;   // x rows
    n0 = blockIdx.x * 128;   // W rows
  }

  const f32x4 z4 = {0.f, 0.f, 0.f, 0.f};
  f32x4 acc[4][4];
#pragma unroll
  for (int i = 0; i < 4; i++)
#pragma unroll
    for (int j = 0; j < 4; j++) acc[i][j] = z4;

  // staging: call j covers LDS rows w*32+j*8 .. +8 (8 rows x 128B = 1KB).
  // lane i -> row (i>>3), chunk slot (i&7); source chunk = slot ^ (row&7).
  const int lrow = lane >> 3;                       // 0..7
  const int scol = ((lane & 7) ^ (lrow & 7)) * 8;   // pre-swizzled src chunk
  const int srowA = m0 + w * 32 + lrow;
  const int srowB = n0 + w * 32 + lrow;
  // fragment read swizzle: row&7 == m16&7 for all t (t*16 offsets)
  const int rsw = m16 & 7;

  for (int k0 = 0; k0 < 1024; k0 += 64) {
    __syncthreads();  // prior MFMA reads of As/Bs complete
#pragma unroll
    for (int j = 0; j < 4; j++) {
      gld_lds16(&Ap[(size_t)(srowA + j * 8) * 1024 + k0 + scol],
                &As[(w * 32 + j * 8) * 64]);
      gld_lds16(&Bp[(size_t)(srowB + j * 8) * 1024 + k0 + scol],
                &Bs[(w * 32 + j * 8) * 64]);
    }
    __syncthreads();  // drains vmcnt -> tiles ready

#pragma unroll
    for (int kk = 0; kk < 2; kk++) {
      bf16x8 af[4], bfr[4];
      const int csw = ((kk * 4) ^ rsw) * 8;  // quad-chunk XOR: quad^rsw low bits
#pragma unroll
      for (int t = 0; t < 4; t++) {
        af[t] = *(const bf16x8*)
            &As[(wm * 64 + t * 16 + m16) * 64 + (((kk * 4 + quad) ^ rsw) * 8)];
        bfr[t] = *(const bf16x8*)
            &Bs[(wn * 64 + t * 16 + m16) * 64 + (((kk * 4 + quad) ^ rsw) * 8)];
      }
      (void)csw;
#pragma unroll
      for (int mt = 0; mt < 4; mt++)
#pragma unroll
        for (int nt = 0; nt < 4; nt++)
          acc[mt][nt] = __builtin_amdgcn_mfma_f32_16x16x32_bf16(
              af[mt], bfr[nt], acc[mt][nt], 0, 0, 0);
    }
  }

  // Epilogue. C/D layout: col(n)=lane&15, row(m)=quad*4+reg.
  if (which < 2) {
    u16* __restrict__ out = which == 0 ? qo : ko;
#pragma unroll
    for (int mt = 0; mt < 4; mt++) {
      const int row = m0 + wm * 64 + mt * 16 + quad * 4;
#pragma unroll
      for (int nt = 0; nt < 4; nt++) {
        const int n = n0 + wn * 64 + nt * 16 + m16;
        f32x4 a = acc[mt][nt];
#pragma unroll
        for (int r = 0; r < 4; r++)
          out[(size_t)(row + r) * 1024 + n] = f2bf(a[r]);
      }
    }
  } else {
    // vt store with swap23 on the within-16 token index (involution):
    // column (...|m16p) holds V[token ...|m16] so flash reads vt linearly
    // and gets the key order its P-fragments produce.
    const int m16p = (m16 & 3) | ((m16 & 4) << 1) | ((m16 & 8) >> 1);
#pragma unroll
    for (int mt = 0; mt < 4; mt++) {
      const int row = m0 + wm * 64 + mt * 16 + quad * 4;  // d index
#pragma unroll
      for (int nt = 0; nt < 4; nt++) {
        const int n = n0 + wn * 64 + nt * 16 + m16p;      // x row (permuted)
        f32x4 a = acc[mt][nt];
#pragma unroll
        for (int r = 0; r < 4; r++)
          vt[(size_t)(row + r) * 4096 + n] = f2bf(a[r]);
      }
    }
  }
}

// ---------------------------------------------------------------------------
// Kernel 2: RoPE in-place, vectorized u16x8 (4 pairs/thread), HW trig:
// v_fract + v_sin/v_cos on revolutions (angle*1/2pi). ~10x fewer VALU ops
// than libm sincosf; angle error <= 4e-4 rad, well under bf16 quantum.
// ---------------------------------------------------------------------------
__global__ __launch_bounds__(256) void rope_inplace(u16* __restrict__ qb,
                                                    u16* __restrict__ kb) {
  u16* buf = blockIdx.y == 0 ? qb : kb;
  const int p = blockIdx.x * 256 + (int)threadIdx.x;
  const int e0 = p * 8;
  const int row = e0 >> 10;
  const int col0 = e0 & 1023;
  const int t = row & 2047;
  const float tf = (float)t;

  u16x8 d = *(const u16x8*)&buf[(size_t)row * 1024 + col0];
  u16x8 o;
#pragma unroll
  for (int j = 0; j < 4; j++) {
    const int i = ((col0 & 63) >> 1) + j;
    // theta/(2pi) = 2^(-i*c) * (1/2pi)
    const float th = fast_exp2(-(float)i * 0.02595256324130752f);
    const float rev = tf * th * 0.15915494309189535f;
    float fr, s, c;
    asm("v_fract_f32 %0, %1" : "=v"(fr) : "v"(rev));
    asm("v_sin_f32 %0, %1" : "=v"(s) : "v"(fr));
    asm("v_cos_f32 %0, %1" : "=v"(c) : "v"(fr));
    const float a0 = bf2f(d[2 * j]), a1 = bf2f(d[2 * j + 1]);
    o[2 * j]     = f2bf(a0 * c - a1 * s);
    o[2 * j + 1] = f2bf(a1 * c + a0 * s);
  }
  *(u16x8*)&buf[(size_t)row * 1024 + col0] = o;
}

// ---------------------------------------------------------------------------
// Kernel 3: causal flash attention — R3 structure (known 51.9us) + 3 edits:
// (a) raw v_exp_f32 (libm exp2f clamp path was a top VALU term),
// (b) vt pre-swap23'd by qkv_gemm -> Vs staging is 4 plain u16x8 stores,
// (c) LPT ordering: longest blocks (qt=31) launch first; 4x-oversubscribed
//     scheduler backfills short blocks into the tail (R3 static pairing left
//     occupancy at 23%). XCD locality kept: id&7 = XCD sees 4 heads.
// In-register P (T12), KVBLK=128, l via ones-MFMA, reg-prefetch K/V.
// ---------------------------------------------------------------------------
__global__ __launch_bounds__(256, 4) void flash_attn(
    const u16* __restrict__ qg, const u16* __restrict__ kg,
    const u16* __restrict__ vt, float* __restrict__ out) {
  __shared__ __align__(16) u16 Ks[128 * 72];   // [key][d]
  __shared__ __align__(16) u16 Vs[64 * 136];   // [d][kperm] (vt already swz)

  const int tid = threadIdx.x, lane = tid & 63, w = tid >> 6;
  const int quad = lane >> 4, m16 = lane & 15;

  // LPT + XCD map: X = id&7 (XCD), qt descends with id so long blocks start
  // first; each XCD covers 4 (b,h) combos (2MB K+V < 4MB L2).
  const int id   = (int)blockIdx.x;
  const int X    = id & 7;
  const int rem  = id >> 3;          // 0..127 within XCD
  const int qt   = 31 - (rem >> 2);
  const int vloc = rem & 3;
  const int v    = X * 4 + vloc;     // (b,h) combo
  const int h    = v & 15;
  const int b    = v >> 4;

  const size_t base  = (size_t)b * 2048 * 1024 + (size_t)h * 64;
  const size_t vbase = (size_t)(h * 64) * 4096 + (size_t)b * 2048;
  const float SC = 0.03125f * LOG2E;
  const f32x4 z4 = {0.f, 0.f, 0.f, 0.f};
  const int srow = tid >> 2, sc = (tid & 3) * 16;

  union { u16x8 u; bf16x8 f; } ones;
#pragma unroll
  for (int k = 0; k < 8; k++) ones.u[k] = 0x3F80;  // bf16 1.0

  const int q0 = qt * 64;
  const int nr = (qt + 2) >> 1;  // rounds of 128 keys

  // Q fragments straight from global (L2-hit; once per block).
  const u16* qsrc = &qg[base + (size_t)(q0 + w * 16 + m16) * 1024 + quad * 8];
  const bf16x8 qf0 = *(const bf16x8*)qsrc;
  const bf16x8 qf1 = *(const bf16x8*)(qsrc + 32);

  // Prefetch round 0 K/V into regs.
  u16x8 kr0, kr1, kr2, kr3, vr0, vr1, vr2, vr3;
  {
    const u16* ks = &kg[base + (size_t)srow * 1024 + sc];
    kr0 = *(const u16x8*)ks; kr1 = *(const u16x8*)(ks + 8);
    const u16* ks2 = ks + (size_t)64 * 1024;
    kr2 = *(const u16x8*)ks2; kr3 = *(const u16x8*)(ks2 + 8);
    const u16* vs = &vt[vbase + (size_t)srow * 4096 + sc];
    vr0 = *(const u16x8*)vs; vr1 = *(const u16x8*)(vs + 8);
    vr2 = *(const u16x8*)(vs + 64); vr3 = *(const u16x8*)(vs + 72);
  }

  f32x4 l4 = z4;  // l[r] = denom for q row qrow0+r (via ones-MFMA)
  f32x4 O[4];
#pragma unroll
  for (int d = 0; d < 4; d++) O[d] = z4;

  const int qrow0 = q0 + w * 16 + quad * 4;  // O store rows
  const int qcol  = q0 + w * 16 + m16;       // this lane's softmax q

  for (int rr = 0; rr < nr; ++rr) {
    const int k0 = rr * 128;
    if (rr) __syncthreads();  // all waves done with prev Ks/Vs
    *(u16x8*)&Ks[srow * 72 + sc] = kr0;
    *(u16x8*)&Ks[srow * 72 + sc + 8] = kr1;
    *(u16x8*)&Ks[(64 + srow) * 72 + sc] = kr2;
    *(u16x8*)&Ks[(64 + srow) * 72 + sc + 8] = kr3;
    *(u16x8*)&Vs[srow * 136 + sc] = vr0;
    *(u16x8*)&Vs[srow * 136 + sc + 8] = vr1;
    *(u16x8*)&Vs[srow * 136 + 64 + sc] = vr2;
    *(u16x8*)&Vs[srow * 136 + 64 + sc + 8] = vr3;
    __syncthreads();
    if (rr + 1 < nr) {  // prefetch next round; overlaps MFMA + softmax
      const u16* ks = &kg[base + (size_t)(k0 + 128 + srow) * 1024 + sc];
      kr0 = *(const u16x8*)ks; kr1 = *(const u16x8*)(ks + 8);
      const u16* ks2 = ks + (size_t)64 * 1024;
      kr2 = *(const u16x8*)ks2; kr3 = *(const u16x8*)(ks2 + 8);
      const u16* vs = &vt[vbase + (size_t)srow * 4096 + k0 + 128 + sc];
      vr0 = *(const u16x8*)vs; vr1 = *(const u16x8*)(vs + 8);
      vr2 = *(const u16x8*)(vs + 64); vr3 = *(const u16x8*)(vs + 72);
    }

    // S^T = K Q^T over 128 keys: S[nt] rows = key nt*16+quad*4+r, col=q
    f32x4 S[8];
#pragma unroll
    for (int nt = 0; nt < 8; nt++) {
      const bf16x8 kf0 = *(const bf16x8*)&Ks[(nt * 16 + m16) * 72 + quad * 8];
      const bf16x8 kf1 =
          *(const bf16x8*)&Ks[(nt * 16 + m16) * 72 + 32 + quad * 8];
      S[nt] = __builtin_amdgcn_mfma_f32_16x16x32_bf16(kf0, qf0, z4, 0, 0, 0);
      S[nt] = __builtin_amdgcn_mfma_f32_16x16x32_bf16(kf1, qf1, S[nt], 0, 0, 0);
    }

    // p = exp2(s*SC); mask only on the last round (covers diag + dead keys)
    const bool lastr = (rr == nr - 1);
    uint32_t W[16];
#pragma unroll
    for (int nt = 0; nt < 8; nt++) {
      float p[4];
#pragma unroll
      for (int r = 0; r < 4; r++) {
        float e = fast_exp2(S[nt][r] * SC);
        const int key = k0 + nt * 16 + quad * 4 + r;
        if (lastr && key > qcol) e = 0.f;
        p[r] = e;
      }
      uint32_t w0, w1;
      asm("v_cvt_pk_bf16_f32 %0, %1, %2" : "=v"(w0) : "v"(p[0]), "v"(p[1]));
      asm("v_cvt_pk_bf16_f32 %0, %1, %2" : "=v"(w1) : "v"(p[2]), "v"(p[3]));
      W[2 * nt] = w0; W[2 * nt + 1] = w1;
    }

    // Assemble PV A-frags: one permlane32_swap pair per 32-key block.
    union { u32v4 u; bf16x8 f; } P[4];
#pragma unroll
    for (int ks = 0; ks < 4; ks++) {
      uint32_t a0 = W[4 * ks], b0 = W[4 * ks + 2];
      uint32_t a1 = W[4 * ks + 1], b1 = W[4 * ks + 3];
      asm("v_permlane32_swap_b32 %0, %1" : "+v"(a0), "+v"(b0));
      asm("v_permlane32_swap_b32 %0, %1" : "+v"(a1), "+v"(b1));
      P[ks].u = (u32v4){a0, a1, b0, b1};
    }

    // l += P * ones  (row sums of rounded P; same row indexing as O)
#pragma unroll
    for (int ks = 0; ks < 4; ks++)
      l4 = __builtin_amdgcn_mfma_f32_16x16x32_bf16(P[ks].f, ones.f, l4,
                                                   0, 0, 0);

    // O += P V  (Vs key order matches P frag order: vt pre-swizzled)
#pragma unroll
    for (int dt = 0; dt < 4; dt++) {
#pragma unroll
      for (int ks = 0; ks < 4; ks++) {
        const bf16x8 vf =
            *(const bf16x8*)&Vs[(dt * 16 + m16) * 136 + ks * 32 + quad * 8];
        O[dt] = __builtin_amdgcn_mfma_f32_16x16x32_bf16(P[ks].f, vf, O[dt],
                                                        0, 0, 0);
      }
    }
  }

  float inv[4];
#pragma unroll
  for (int r = 0; r < 4; r++) inv[r] = 1.0f / l4[r];

#pragma unroll
  for (int dt = 0; dt < 4; dt++)
#pragma unroll
    for (int r = 0; r < 4; r++)
      out[base + (size_t)(qrow0 + r) * 1024 + dt * 16 + m16] =
          O[dt][r] * inv[r];
}

extern "C" void kernel_launch(void* const* d_in, const int* in_sizes, int n_in,
                              void* d_out, int out_size, void* d_ws, size_t ws_size,
                              hipStream_t stream) {
  const float* x  = (const float*)d_in[0];
  const float* Wq = (const float*)d_in[1];
  const float* Wk = (const float*)d_in[2];
  const float* Wv = (const float*)d_in[3];
  u16* qb  = (u16*)d_ws;                    // [4096][1024] bf16
  u16* kb  = qb  + (size_t)4096 * 1024;     // [4096][1024] bf16
  u16* vtw = kb  + (size_t)4096 * 1024;     // [1024][4096] bf16 (V^T, swap23)
  u16* xc  = vtw + (size_t)4096 * 1024;     // bf16 inputs
  u16* wqc = xc  + (size_t)4096 * 1024;
  u16* wkc = wqc + (size_t)1024 * 1024;
  u16* wvc = wkc + (size_t)1024 * 1024;

  f32_to_bf16<<<dim3(2048, 4), 256, 0, stream>>>(x, Wq, Wk, Wv,
                                                 xc, wqc, wkc, wvc);
  qkv_gemm<<<dim3(8, 32, 3), 256, 0, stream>>>(xc, wqc, wkc, wvc,
                                               qb, kb, vtw);
  rope_inplace<<<dim3(2048, 2), 256, 0, stream>>>(qb, kb);
  flash_attn<<<dim3(1024, 1, 1), 256, 0, stream>>>(qb, kb, vtw, (float*)d_out);
}